// Round 9
// baseline (3083.997 us; speedup 1.0000x reference)
//
#include <hip/hip_runtime.h>
#include <hip/hip_bf16.h>
#include <stdint.h>

// Problem constants
#define NN 20000      // nodes
#define NE 640000     // edges
#define HID 512
#define MID 4352
#define VOC 8192

typedef __attribute__((ext_vector_type(4))) float f32x4;
typedef __attribute__((ext_vector_type(8))) short bf16x8;

__device__ __forceinline__ unsigned short f2bf(float f) {
  unsigned int u = __float_as_uint(f);
  u += 0x7fffu + ((u >> 16) & 1u);   // round-to-nearest-even
  return (unsigned short)(u >> 16);
}

// ---------------- detect edge_index storage width ----------------
__global__ void k_detect64(const int* __restrict__ ei32, int* __restrict__ flag) {
  __shared__ int any_nz;
  if (threadIdx.x == 0) any_nz = 0;
  __syncthreads();
  int v = ei32[2 * threadIdx.x + 1];
  if (v != 0) atomicOr(&any_nz, 1);
  __syncthreads();
  if (threadIdx.x == 0) *flag = (any_nz == 0) ? 1 : 0;  // 1 => int64 layout
}

__global__ void k_zero_i32(int* __restrict__ p, int n) {
  int i = blockIdx.x * blockDim.x + threadIdx.x;
  if (i < n) p[i] = 0;
}

__global__ void k_count(const int* __restrict__ ei, const int* __restrict__ flag,
                        int* __restrict__ deg) {
  int e = blockIdx.x * blockDim.x + threadIdx.x;
  if (e >= NE) return;
  int is64 = *flag;
  int d = is64 ? ei[2 * (NE + e)] : ei[NE + e];
  if ((unsigned)d >= NN) return;
  atomicAdd(&deg[d], 1);
}

__global__ __launch_bounds__(1024)
void k_scan(const int* __restrict__ deg, int* __restrict__ offs, int* __restrict__ cursor) {
  __shared__ int part[1024];
  const int t = threadIdx.x;
  const int CH = (NN + 1023) / 1024;  // 20
  const int base = t * CH;
  int s = 0;
  for (int i = 0; i < CH; ++i) { int idx = base + i; if (idx < NN) s += deg[idx]; }
  part[t] = s;
  __syncthreads();
  for (int off = 1; off < 1024; off <<= 1) {
    int v = (t >= off) ? part[t - off] : 0;
    __syncthreads();
    part[t] += v;
    __syncthreads();
  }
  int run = (t == 0) ? 0 : part[t - 1];  // exclusive prefix
  for (int i = 0; i < CH; ++i) {
    int idx = base + i;
    if (idx < NN) { offs[idx] = run; cursor[idx] = run; run += deg[idx]; }
  }
}

__global__ void k_fill(const int* __restrict__ ei, const int* __restrict__ flag,
                       int* __restrict__ cursor, int* __restrict__ csr) {
  int e = blockIdx.x * blockDim.x + threadIdx.x;
  if (e >= NE) return;
  int is64 = *flag;
  int s, d;
  if (is64) { s = ei[2 * e]; d = ei[2 * (NE + e)]; }
  else      { s = ei[e];     d = ei[NE + e]; }
  if ((unsigned)s >= NN || (unsigned)d >= NN) return;
  int pos = atomicAdd(&cursor[d], 1);
  csr[pos] = s;
}

__global__ void k_f32_to_bf16(const float4* __restrict__ src, uint2* __restrict__ dst, int n4) {
  int i = blockIdx.x * blockDim.x + threadIdx.x;
  int stride = gridDim.x * blockDim.x;
  for (; i < n4; i += stride) {
    float4 v = src[i];
    uint2 o;
    o.x = (unsigned)f2bf(v.x) | ((unsigned)f2bf(v.y) << 16);
    o.y = (unsigned)f2bf(v.z) | ((unsigned)f2bf(v.w) << 16);
    dst[i] = o;
  }
}

// ---------------- fused gather: hb = bf16(x_i + sum bf16(x_j)) ----------------
__global__ __launch_bounds__(256)
void k_gather2(const float4* __restrict__ x4, const uint4* __restrict__ xb4,
               const int* __restrict__ offs, const int* __restrict__ deg,
               const int* __restrict__ csr, uint4* __restrict__ hb4) {
  const int wid = blockIdx.x * (blockDim.x >> 6) + (threadIdx.x >> 6);
  if (wid >= NN) return;
  const int lane = threadIdx.x & 63;
  float4 s0 = x4[(long long)wid * 128 + lane * 2];
  float4 s1 = x4[(long long)wid * 128 + lane * 2 + 1];
  float a0 = s0.x, a1 = s0.y, a2 = s0.z, a3 = s0.w;
  float a4 = s1.x, a5 = s1.y, a6 = s1.z, a7 = s1.w;
  const int beg = offs[wid];
  const int dc  = deg[wid];
  for (int j = 0; j < dc; ++j) {
    int s = csr[beg + j];
    uint4 v = xb4[(long long)s * 64 + lane];
    a0 += __uint_as_float(v.x << 16); a1 += __uint_as_float(v.x & 0xffff0000u);
    a2 += __uint_as_float(v.y << 16); a3 += __uint_as_float(v.y & 0xffff0000u);
    a4 += __uint_as_float(v.z << 16); a5 += __uint_as_float(v.z & 0xffff0000u);
    a6 += __uint_as_float(v.w << 16); a7 += __uint_as_float(v.w & 0xffff0000u);
  }
  uint4 o;
  o.x = (unsigned)f2bf(a0) | ((unsigned)f2bf(a1) << 16);
  o.y = (unsigned)f2bf(a2) | ((unsigned)f2bf(a3) << 16);
  o.z = (unsigned)f2bf(a4) | ((unsigned)f2bf(a5) << 16);
  o.w = (unsigned)f2bf(a6) | ((unsigned)f2bf(a7) << 16);
  hb4[(long long)wid * 64 + lane] = o;
}

// =================== 256x256 8-phase bf16 GEMM, 4 waves of 128x128 ===================
// C[M,N] = A[M,K] * B[N,K]^T + bias.  BK=64, 256 thr = 4 waves (2Mx2N),
// per-wave 128x128 output (acc 256 VGPR; 1 wave/SIMD, launch_bounds(256,1)).
// Rationale: LDS-read volume = (Mw+Nw)*BK*2 per wave -> 4x(128+128) = 128KB/K-tile
// vs 8-wave 192KB. LDS pipe (~2050cyc) now balances MFMA pipe (~2050cyc).
// Same proven R5/R8 skeleton: 8 phases / 2 K-tiles, seg-swizzle (0 conflicts),
// counted vmcnt(4) at P4/P8 before barrier only (per-wave vmcnt + barrier
// collectivizes), stagger gives each half-tile >=1 phase slack.

#define SBAR  __builtin_amdgcn_s_barrier()
#define SCHB  __builtin_amdgcn_sched_barrier(0)
#define VMC(n) asm volatile("s_waitcnt vmcnt(" #n ")" ::: "memory")
#define PRIO1 __builtin_amdgcn_s_setprio(1)
#define PRIO0 __builtin_amdgcn_s_setprio(0)

// read A half (4 frags x 2 ks) at quad qm
#define READ_A(qm, bufc) \
  _Pragma("unroll") for (int m_ = 0; m_ < 4; ++m_) { \
    const char* p_ = (bufc) + aOff + (qm) * 8192 + m_ * 2048; \
    aF[m_][0] = *(const bf16x8*)(p_ + sg0); \
    aF[m_][1] = *(const bf16x8*)(p_ + sg1); \
  }

// read B half (4 frags x 2 ks) at quad qn
#define READ_B(qn, bufc, DST) \
  _Pragma("unroll") for (int n_ = 0; n_ < 4; ++n_) { \
    const char* p_ = (bufc) + 32768 + bOff + (qn) * 8192 + n_ * 2048; \
    DST[n_][0] = *(const bf16x8*)(p_ + sg0); \
    DST[n_][1] = *(const bf16x8*)(p_ + sg1); \
  }

// 32 MFMA: quad (qm,qn); ks-outer so dependent ks1 chains are 16 issues apart
#define MFMA_Q(qm, qn, BQ) \
  _Pragma("unroll") for (int ks_ = 0; ks_ < 2; ++ks_) \
    _Pragma("unroll") for (int m_ = 0; m_ < 4; ++m_) \
      _Pragma("unroll") for (int n_ = 0; n_ < 4; ++n_) \
        acc[(qm)*4+m_][(qn)*4+n_] = __builtin_amdgcn_mfma_f32_16x16x32_bf16( \
            aF[m_][ks_], BQ[n_][ks_], acc[(qm)*4+m_][(qn)*4+n_], 0, 0, 0);

// stage one 16KB half-tile: 4 gload_lds per thread (chunk c = j_*4 + w)
#define STAGE_A(bufc, kt, ha) \
  _Pragma("unroll") for (int j_ = 0; j_ < 4; ++j_) { \
    int c_ = j_ * 4 + w; \
    int rl_ = (ha) * 128 + c_ * 8 + stSub; \
    int gr_ = aRow0 + rl_; if (gr_ > Mm1) gr_ = Mm1; \
    __builtin_amdgcn_global_load_lds( \
      (const __attribute__((address_space(1))) void*)(A + (long long)gr_ * K + (kt) * 64 + stSeg8), \
      (__attribute__((address_space(3))) void*)((bufc) + (ha) * 16384 + c_ * 1024), \
      16, 0, 0); \
  }

#define STAGE_B(bufc, kt, ha) \
  _Pragma("unroll") for (int j_ = 0; j_ < 4; ++j_) { \
    int c_ = j_ * 4 + w; \
    int rl_ = (ha) * 128 + c_ * 8 + stSub; \
    int gr_ = bRow0 + rl_; \
    __builtin_amdgcn_global_load_lds( \
      (const __attribute__((address_space(1))) void*)(B + (long long)gr_ * K + (kt) * 64 + stSeg8), \
      (__attribute__((address_space(3))) void*)((bufc) + 32768 + (ha) * 16384 + c_ * 1024), \
      16, 0, 0); \
  }

template<bool OUT_BF16>
__global__ __launch_bounds__(256, 1)
void k_gemm256(const unsigned short* __restrict__ A,   // [M,K] bf16
               const unsigned short* __restrict__ B,   // [N,K] bf16
               const float* __restrict__ bias,         // [N]
               void* __restrict__ C,                   // [M,N] f32 or bf16
               int M, int N, int K)
{
  __shared__ __align__(16) char lds[131072];   // 2 x (A 32KB + B 32KB)

  const int tid  = threadIdx.x;
  const int lane = tid & 63;
  const int w    = tid >> 6;       // 0..3
  const int wr   = w >> 1;         // 0..1  (M)
  const int wc   = w & 1;          // 0..1  (N)

  // grid mapping: bn-chunk per XCD if possible, else m204 bijective swizzle
  const int nwg  = gridDim.x * gridDim.y;
  const int orig = blockIdx.y * gridDim.x + blockIdx.x;
  int bn, bm;
  if ((gridDim.x & 7) == 0 && (nwg & 7) == 0) {
    const int xcd = orig & 7;
    const int j   = orig >> 3;
    const int chunk = gridDim.x >> 3;
    bn = xcd * chunk + (j % chunk);
    bm = j / chunk;
  } else {
    const int q = nwg >> 3, r = nwg & 7;
    const int xcd = orig & 7, land = orig >> 3;
    const int nid = (xcd < r ? xcd * (q + 1) : r * (q + 1) + (xcd - r) * q) + land;
    bn = nid % gridDim.x;
    bm = nid / gridDim.x;
  }

  // per-lane constants
  const int lm = lane & 15;
  const int lk = lane >> 4;                       // 0..3
  const int l7 = lane & 7;
  const int sg0 = ((lk    ) ^ l7) * 16;           // swizzled seg byte off, ks=0
  const int sg1 = ((lk + 4) ^ l7) * 16;           // ks=1
  const int aOff = (wr * 128 + lm) * 128;         // A read base (bytes)
  const int bOff = (wc * 128 + lm) * 128;         // B read base (bytes)
  const int stSub  = lane >> 3;                   // 0..7
  const int stSeg8 = ((lane & 7) ^ stSub) * 8;    // pre-swizzled source seg (elems)
  const int aRow0 = bm * 256;
  const int bRow0 = bn * 256;
  const int Mm1 = M - 1;

  char* lb0 = (char*)lds;            // even K-tiles
  char* lb1 = (char*)lds + 65536;    // odd K-tiles

  f32x4 acc[8][8] = {};
  bf16x8 aF[4][2], bFa[4][2], bFb[4][2];

  const int nkt = K >> 6;            // 64-wide K tiles (even count for 512/4352)
  const int nit = nkt >> 1;

  // prologue: tile0 full + tile1.A-h0 (20 loads/thread); drain tile0 -> 4 left
  STAGE_A(lb0, 0, 0); STAGE_A(lb0, 0, 1); STAGE_B(lb0, 0, 0); STAGE_B(lb0, 0, 1);
  STAGE_A(lb1, 1, 0);
  VMC(4);
  SBAR;

  for (int i = 0; i < nit; ++i) {
    const int ktO = 2 * i + 1;
    int ktE2 = 2 * i + 2; if (ktE2 >= nkt) ktE2 = nkt - 1;  // clamped junk on last iter
    int ktO2 = 2 * i + 3; if (ktO2 >= nkt) ktO2 = nkt - 1;
    // P1: tile E quad(0,0)
    READ_A(0, lb0); READ_B(0, lb0, bFa);
    STAGE_A(lb1, ktO, 1);
    SBAR; PRIO1; MFMA_Q(0, 0, bFa); PRIO0; SCHB; SBAR;
    // P2: quad(0,1)
    READ_B(1, lb0, bFb);
    STAGE_B(lb1, ktO, 0);
    SBAR; PRIO1; MFMA_Q(0, 1, bFb); PRIO0; SCHB; SBAR;
    // P3: quad(1,1)
    READ_A(1, lb0);
    STAGE_B(lb1, ktO, 1);
    SBAR; PRIO1; MFMA_Q(1, 1, bFb); PRIO0; SCHB; SBAR;
    // P4: quad(1,0); drain tile O stages (leave P4's own 4)
    STAGE_A(lb0, ktE2, 0);
    SBAR; PRIO1; MFMA_Q(1, 0, bFa); PRIO0; SCHB; VMC(4); SBAR;
    // P5: tile O quad(0,0)
    READ_A(0, lb1); READ_B(0, lb1, bFa);
    STAGE_A(lb0, ktE2, 1);
    SBAR; PRIO1; MFMA_Q(0, 0, bFa); PRIO0; SCHB; SBAR;
    // P6: quad(0,1)
    READ_B(1, lb1, bFb);
    STAGE_B(lb0, ktE2, 0);
    SBAR; PRIO1; MFMA_Q(0, 1, bFb); PRIO0; SCHB; SBAR;
    // P7: quad(1,1)
    READ_A(1, lb1);
    STAGE_B(lb0, ktE2, 1);
    SBAR; PRIO1; MFMA_Q(1, 1, bFb); PRIO0; SCHB; SBAR;
    // P8: quad(1,0); drain tile E' stages
    STAGE_A(lb1, ktO2, 0);
    SBAR; PRIO1; MFMA_Q(1, 0, bFa); PRIO0; SCHB; VMC(4); SBAR;
  }

  // epilogue: C[row, col] = acc + bias
#pragma unroll
  for (int jn = 0; jn < 8; ++jn) {
    const int col = bn * 256 + wc * 128 + jn * 16 + lm;
    const float bv = bias[col];
#pragma unroll
    for (int im = 0; im < 8; ++im) {
      const int row0 = bm * 256 + wr * 128 + im * 16 + lk * 4;
#pragma unroll
      for (int jj = 0; jj < 4; ++jj) {
        const int row = row0 + jj;
        if (row < M) {
          const float v = acc[im][jn][jj] + bv;
          if (OUT_BF16)
            __builtin_nontemporal_store(f2bf(v), &((unsigned short*)C)[(long long)row * N + col]);
          else
            __builtin_nontemporal_store(v, &((float*)C)[(long long)row * N + col]);
        }
      }
    }
  }
}

extern "C" void kernel_launch(void* const* d_in, const int* in_sizes, int n_in,
                              void* d_out, int out_size, void* d_ws, size_t ws_size,
                              hipStream_t stream) {
  const float* x  = (const float*)d_in[0];
  const int*   ei = (const int*)d_in[1];      // int32 or int64 — detected on device
  const float* W1 = (const float*)d_in[2];
  const float* b1 = (const float*)d_in[3];
  const float* W2 = (const float*)d_in[4];
  const float* b2 = (const float*)d_in[5];
  float* out = (float*)d_out;
  char* ws = (char*)d_ws;

  // workspace layout (bytes, 16B-aligned)
  int* flag            = (int*)(ws + 0);                    // 256
  int* deg             = (int*)(ws + 256);                  // 80,000
  int* offs            = (int*)(ws + 80256);                // 80,000
  int* cursor          = (int*)(ws + 160256);               // 80,000
  int* csr             = (int*)(ws + 240256);               // 2,560,000
  unsigned short* xb   = (unsigned short*)(ws + 2800256);   // 20,480,000
  unsigned short* hb   = (unsigned short*)(ws + 23280256);  // 20,480,000
  unsigned short* w1b  = (unsigned short*)(ws + 43760256);  //  4,456,448
  unsigned short* w2b  = (unsigned short*)(ws + 48216704);  // 71,303,168
  const size_t h1_off  = 119519872;
  if (ws_size < h1_off + (size_t)256 * MID * 2) return;
  unsigned short* h1b  = (unsigned short*)(ws + h1_off);

  long long rem = (long long)ws_size - (long long)h1_off;
  int max_rows = (int)(rem / ((long long)MID * 2));
  max_rows = (max_rows / 256) * 256;
  if (max_rows > 20224) max_rows = 20224;

  // 0) detect edge_index width
  k_detect64<<<1, 256, 0, stream>>>(ei, flag);

  // 1) CSR build
  k_zero_i32<<<(NN + 255) / 256, 256, 0, stream>>>(deg, NN);
  k_count<<<(NE + 255) / 256, 256, 0, stream>>>(ei, flag, deg);
  k_scan<<<1, 1024, 0, stream>>>(deg, offs, cursor);
  k_fill<<<(NE + 255) / 256, 256, 0, stream>>>(ei, flag, cursor, csr);

  // 2) conversions to bf16 (x first: gather depends on it)
  k_f32_to_bf16<<<2048, 256, 0, stream>>>((const float4*)x,  (uint2*)xb,  NN * HID / 4);
  k_f32_to_bf16<<<1024, 256, 0, stream>>>((const float4*)W1, (uint2*)w1b, MID * HID / 4);
  k_f32_to_bf16<<<2048, 256, 0, stream>>>((const float4*)W2, (uint2*)w2b, VOC * MID / 4);

  // 3) fused gather: hb = bf16(x_i + sum_j bf16(x_j))
  k_gather2<<<(NN + 3) / 4, 256, 0, stream>>>((const float4*)x, (const uint4*)xb,
                                              offs, deg, csr, (uint4*)hb);

  // 4+5) chunked GEMM1 -> GEMM2 over M (usually a single chunk)
  for (int r0 = 0; r0 < NN; r0 += max_rows) {
    int mrows = (NN - r0 < max_rows) ? (NN - r0) : max_rows;
    dim3 g1(MID / 256, (mrows + 255) / 256);
    k_gemm256<true><<<g1, 256, 0, stream>>>(hb + (size_t)r0 * HID, w1b, b1,
                                            (void*)h1b, mrows, MID, HID);
    dim3 g2(VOC / 256, (mrows + 255) / 256);
    k_gemm256<false><<<g2, 256, 0, stream>>>(h1b, w2b, b2,
                                             (void*)(out + (size_t)r0 * VOC), mrows, VOC, MID);
  }
}